// Round 12
// baseline (129.389 us; speedup 1.0000x reference)
//
#include <hip/hip_runtime.h>
#include <hip/hip_bf16.h>
#include <cstdint>

#define EPS 1e-5f
#define NEG 0.1f

using bfrag = __attribute__((ext_vector_type(8))) short;   // 8 bf16
using f32x4 = __attribute__((ext_vector_type(4))) float;
typedef unsigned short ushort_t;

// geometry
constexpr int B_  = 4,  CIN = 64, H0 = 192, W0 = 192;
constexpr int C_  = 128, H_ = 96, W_ = 96;
constexpr int HW_ = H_ * W_;      // 9216
constexpr int HW0 = H0 * W0;      // 36864
constexpr int XS  = 194;          // padded xcl dim (1-px halo)
constexpr int TS  = 98;           // padded t1/t3 dim (1-px halo)
constexpr int VSTR = 1160;        // dcn val row stride (bf16)

__device__ __forceinline__ ushort_t f2bf(float f) {
  unsigned u = __builtin_bit_cast(unsigned, f);
  u += 0x7fffu + ((u >> 16) & 1u);
  return (ushort_t)(u >> 16);
}
__device__ __forceinline__ float loF(unsigned d) {
  return __builtin_bit_cast(float, d << 16);
}
__device__ __forceinline__ float hiF(unsigned d) {
  return __builtin_bit_cast(float, d & 0xFFFF0000u);
}
__device__ __forceinline__ bfrag loadB(const ushort_t* p) {
  return *(const bfrag*)p;
}

#define MFMA4(A0, A1, B0, B1, ACC)                                             \
  ACC[0][0] = __builtin_amdgcn_mfma_f32_16x16x32_bf16(A0, B0, ACC[0][0], 0, 0, 0); \
  ACC[0][1] = __builtin_amdgcn_mfma_f32_16x16x32_bf16(A0, B1, ACC[0][1], 0, 0, 0); \
  ACC[1][0] = __builtin_amdgcn_mfma_f32_16x16x32_bf16(A1, B0, ACC[1][0], 0, 0, 0); \
  ACC[1][1] = __builtin_amdgcn_mfma_f32_16x16x32_bf16(A1, B1, ACC[1][1], 0, 0, 0);

// ---------------------------------------------------------------------------
// k_prep: wave-order weight packing + halo zeroing, ONE launch (1883 blocks).
// ---------------------------------------------------------------------------
__global__ __launch_bounds__(256)
void k_prep(const float* __restrict__ w_r1, const float* __restrict__ w_r2,
            const float* __restrict__ w_off, const float* __restrict__ w_dcn,
            const float* __restrict__ w_rs, const float* __restrict__ w_c2,
            const float* __restrict__ w_ds,
            ushort_t* __restrict__ wp_r1, ushort_t* __restrict__ wp_r2,
            ushort_t* __restrict__ wp_off, ushort_t* __restrict__ wp_dcn,
            ushort_t* __restrict__ wp_rs, ushort_t* __restrict__ wp_c2,
            ushort_t* __restrict__ wp_ds,
            ushort_t* __restrict__ xclp, ushort_t* __restrict__ t1p,
            ushort_t* __restrict__ t3p) {
  int bi = blockIdx.x;
  int tid = (int)threadIdx.x;
  auto pack3w = [&](const float* w, ushort_t* wp, int O, int C, int Opad, int b0) {
    int idx = (bi - b0) * 256 + tid;
    int e = idx & 7;
    int lane = (idx >> 3) & 63;
    int fb = idx >> 9;
    int OBQ = Opad / 16;
    int obq = fb % OBQ, s = fb / OBQ;
    int lr = lane & 15, lq = lane >> 4;
    int o = obq * 16 + lr;
    int cq = s % (C / 32), tap = s / (C / 32);
    int c = cq * 32 + lq * 8 + e;
    wp[idx] = (o < O) ? f2bf(w[((size_t)o * C + c) * 9 + tap]) : (ushort_t)0;
  };
  auto pack1w = [&](const float* w, ushort_t* wp, int O, int C, int Opad, int b0) {
    int idx = (bi - b0) * 256 + tid;
    int e = idx & 7;
    int lane = (idx >> 3) & 63;
    int fb = idx >> 9;
    int OBQ = Opad / 16;
    int obq = fb % OBQ, s = fb / OBQ;
    int lr = lane & 15, lq = lane >> 4;
    int o = obq * 16 + lr;
    int c = s * 32 + lq * 8 + e;
    wp[idx] = (o < O) ? f2bf(w[(size_t)o * C + c]) : (ushort_t)0;
  };
  auto border = [&](ushort_t* buf, int N, int C, int b0) {
    int idx = (bi - b0) * 256 + tid;
    int per = 4 * N - 4;
    if (idx >= per * 4) return;
    int b = idx / per, e = idx - b * per;
    int r, s;
    if (e < N) { r = 0; s = e; }
    else if (e < 2 * N) { r = N - 1; s = e - N; }
    else if (e < 3 * N - 2) { r = e - 2 * N + 1; s = 0; }
    else { r = e - (3 * N - 2) + 1; s = N - 1; }
    uint4* p = (uint4*)(buf + ((size_t)(b * N + r) * N + s) * C);
#pragma unroll
    for (int t = 0; t < 16; ++t) { if (t < C / 8) p[t] = make_uint4(0, 0, 0, 0); }
  };
  if      (bi <  288) pack3w(w_r1,  wp_r1, 128,  64, 128, 0);
  else if (bi <  864) pack3w(w_r2,  wp_r2, 128, 128, 128, 288);
  else if (bi < 1152) pack3w(w_off, wp_off, 54, 128,  64, 864);
  else if (bi < 1728) pack3w(w_dcn, wp_dcn, 128, 128, 128, 1152);
  else if (bi < 1760) pack1w(w_rs,  wp_rs, 128,  64, 128, 1728);
  else if (bi < 1824) pack1w(w_c2,  wp_c2, 128, 128, 128, 1760);
  else if (bi < 1856) pack1w(w_ds,  wp_ds, 128,  64, 128, 1824);
  else if (bi < 1869) border(xclp, XS, 64, 1856);
  else if (bi < 1876) border(t1p, TS, 128, 1869);
  else                border(t3p, TS, 128, 1876);
}

// ---------------------------------------------------------------------------
// x [4,64,192,192] fp32 NCHW -> xclp [4,194,194,64] bf16 (interior)
// ---------------------------------------------------------------------------
__global__ __launch_bounds__(256)
void k_xcl(const float* __restrict__ x, ushort_t* __restrict__ xclp) {
  __shared__ float tile[64][65];
  int tx = threadIdx.x, ty = threadIdx.y;
  int cx = blockIdx.x, y = blockIdx.y, b = blockIdx.z;
  const float* src = x + (size_t)b * CIN * HW0 + (size_t)y * W0 + cx * 64;
#pragma unroll
  for (int r = 0; r < 16; ++r) {
    int ch = r * 4 + ty;
    tile[ch][tx] = src[(size_t)ch * HW0 + tx];
  }
  __syncthreads();
  ushort_t* dst = xclp + ((size_t)(b * XS + y + 1) * XS + cx * 64 + 1) * 64;
#pragma unroll
  for (int r = 0; r < 16; ++r) {
    int pp = r * 4 + ty;
    dst[(size_t)pp * 64 + tx] = f2bf(tile[tx][pp]);
  }
}

// ---------------------------------------------------------------------------
// K1: conv3x3 s2 p1 (64->128) + BN + LReLU.  xclp -> t1p.
// LDS-staged A (swizzle key (px>>1)&7), wave-order B.
// ---------------------------------------------------------------------------
__global__ __launch_bounds__(256)
void k_conv1(const ushort_t* __restrict__ xclp, const ushort_t* __restrict__ wp,
             const float* __restrict__ bnp, ushort_t* __restrict__ t1p) {
  __shared__ ushort_t at[3 * 66 * 64];     // 25344 B
  int tid = threadIdx.x, lane = tid & 63, wv = tid >> 6;
  int lr = lane & 15, lq = lane >> 4, ob = wv * 32;
  int j0 = blockIdx.x * 32, i = blockIdx.y, b = blockIdx.z;
  for (int t = tid; t < 1584; t += 256) {
    int ky = t / 528, r = t - ky * 528;
    int p = r >> 3, c8 = r & 7;
    const char* src = (const char*)(xclp +
        ((size_t)(b * XS + 2 * i + ky) * XS + 2 * j0) * 64) + p * 128 + c8 * 16;
    int db = ((ky * 66 + p) * 128 + c8 * 16) ^ (((p >> 1) & 7) << 4);
    *(uint4*)((char*)at + db) = *(const uint4*)src;
  }
  __syncthreads();
  f32x4 acc[2][2] = {};
#pragma unroll
  for (int tap = 0; tap < 9; ++tap) {
    int ky = tap / 3, kx = tap - 3 * ky;
    int pxa = 2 * lr + kx, pxb = 2 * (16 + lr) + kx;
#pragma unroll
    for (int cq = 0; cq < 2; ++cq) {
      bfrag a0 = *(const bfrag*)((const char*)at +
          (((ky * 66 + pxa) * 128 + cq * 64 + lq * 16) ^ (((pxa >> 1) & 7) << 4)));
      bfrag a1 = *(const bfrag*)((const char*)at +
          (((ky * 66 + pxb) * 128 + cq * 64 + lq * 16) ^ (((pxb >> 1) & 7) << 4)));
      int s = tap * 2 + cq;
      bfrag b0 = loadB(wp + (size_t)(s * 8 + wv * 2) * 512 + lane * 8);
      bfrag b1 = loadB(wp + (size_t)(s * 8 + wv * 2 + 1) * 512 + lane * 8);
      MFMA4(a0, a1, b0, b1, acc);
    }
  }
  ushort_t* dst = t1p + ((size_t)(b * TS + i + 1) * TS + j0 + 1) * 128;
#pragma unroll
  for (int nf = 0; nf < 2; ++nf) {
    int o = ob + nf * 16 + lr;
    float inv = bnp[o] * rsqrtf(bnp[384 + o] + EPS);
    float bb = bnp[128 + o] - bnp[256 + o] * inv;
#pragma unroll
    for (int mf = 0; mf < 2; ++mf)
#pragma unroll
      for (int jj = 0; jj < 4; ++jj) {
        int pix = mf * 16 + 4 * lq + jj;
        float r = acc[mf][nf][jj] * inv + bb;
        r = r >= 0.f ? r : NEG * r;
        dst[(size_t)pix * 128 + o] = f2bf(r);
      }
  }
}

// ---------------------------------------------------------------------------
// K2: conv3x3 s1 p1 (128->128)+BN + 1x1 s2 shortcut+BN, add, LReLU -> t3p
// ---------------------------------------------------------------------------
__global__ __launch_bounds__(256)
void k_conv2(const ushort_t* __restrict__ t1p, const ushort_t* __restrict__ xclp,
             const ushort_t* __restrict__ wp2, const ushort_t* __restrict__ wprs,
             const float* __restrict__ bn2p, const float* __restrict__ bnsp,
             ushort_t* __restrict__ t3p) {
  __shared__ ushort_t at[3 * 34 * 128];    // 26112 B
  int tid = threadIdx.x, lane = tid & 63, wv = tid >> 6;
  int lr = lane & 15, lq = lane >> 4, ob = wv * 32;
  int j0 = blockIdx.x * 32, i = blockIdx.y, b = blockIdx.z;
  for (int t = tid; t < 1632; t += 256) {
    int ky = t / 544, r = t - ky * 544;
    int p = r >> 4, c16 = r & 15;
    const char* src = (const char*)(t1p +
        ((size_t)(b * TS + i + ky) * TS + j0) * 128) + p * 256 + c16 * 16;
    int db = ((ky * 34 + p) * 256 + c16 * 16) ^ ((p & 7) << 4);
    *(uint4*)((char*)at + db) = *(const uint4*)src;
  }
  __syncthreads();
  f32x4 acc[2][2] = {};
  f32x4 acs[2][2] = {};
#pragma unroll
  for (int tap = 0; tap < 9; ++tap) {
    int ky = tap / 3, kx = tap - 3 * ky;
    int pxa = lr + kx, pxb = 16 + lr + kx;
#pragma unroll
    for (int cq = 0; cq < 4; ++cq) {
      bfrag a0 = *(const bfrag*)((const char*)at +
          (((ky * 34 + pxa) * 256 + cq * 64 + lq * 16) ^ ((pxa & 7) << 4)));
      bfrag a1 = *(const bfrag*)((const char*)at +
          (((ky * 34 + pxb) * 256 + cq * 64 + lq * 16) ^ ((pxb & 7) << 4)));
      int s = tap * 4 + cq;
      bfrag b0 = loadB(wp2 + (size_t)(s * 8 + wv * 2) * 512 + lane * 8);
      bfrag b1 = loadB(wp2 + (size_t)(s * 8 + wv * 2 + 1) * 512 + lane * 8);
      MFMA4(a0, a1, b0, b1, acc);
    }
  }
  {
    const ushort_t* rowp = xclp + (size_t)(b * XS + 2 * i + 1) * XS * 64;
    const ushort_t* pa = rowp + (size_t)(2 * (j0 + lr) + 1) * 64 + 8 * lq;
    const ushort_t* pb = rowp + (size_t)(2 * (j0 + 16 + lr) + 1) * 64 + 8 * lq;
#pragma unroll
    for (int sq = 0; sq < 2; ++sq) {
      bfrag a0 = loadB(pa + sq * 32);
      bfrag a1 = loadB(pb + sq * 32);
      bfrag b0 = loadB(wprs + (size_t)(sq * 8 + wv * 2) * 512 + lane * 8);
      bfrag b1 = loadB(wprs + (size_t)(sq * 8 + wv * 2 + 1) * 512 + lane * 8);
      MFMA4(a0, a1, b0, b1, acs);
    }
  }
  ushort_t* dst = t3p + ((size_t)(b * TS + i + 1) * TS + j0 + 1) * 128;
#pragma unroll
  for (int nf = 0; nf < 2; ++nf) {
    int o = ob + nf * 16 + lr;
    float i2 = bn2p[o] * rsqrtf(bn2p[384 + o] + EPS);
    float b2 = bn2p[128 + o] - bn2p[256 + o] * i2;
    float is = bnsp[o] * rsqrtf(bnsp[384 + o] + EPS);
    float bs = bnsp[128 + o] - bnsp[256 + o] * is;
#pragma unroll
    for (int mf = 0; mf < 2; ++mf)
#pragma unroll
      for (int jj = 0; jj < 4; ++jj) {
        int pix = mf * 16 + 4 * lq + jj;
        float h = acc[mf][nf][jj] * i2 + b2 + acs[mf][nf][jj] * is + bs;
        h = h >= 0.f ? h : NEG * h;
        dst[(size_t)pix * 128 + o] = f2bf(h);
      }
  }
}

// ---------------------------------------------------------------------------
// K3: conv3x3 s1 p1 (128->54, pad 64) + bias -> offb; LDS-staged like conv2.
// ---------------------------------------------------------------------------
__global__ __launch_bounds__(128)
void k_convoff(const ushort_t* __restrict__ t3p, const ushort_t* __restrict__ wp,
               const float* __restrict__ boff, float* __restrict__ offb) {
  __shared__ ushort_t at[3 * 34 * 128];    // 26112 B
  int tid = threadIdx.x, lane = tid & 63, wv = tid >> 6;
  int lr = lane & 15, lq = lane >> 4, ob = wv * 32;
  int j0 = blockIdx.x * 32, i = blockIdx.y, b = blockIdx.z;
  for (int t = tid; t < 1632; t += 128) {
    int ky = t / 544, r = t - ky * 544;
    int p = r >> 4, c16 = r & 15;
    const char* src = (const char*)(t3p +
        ((size_t)(b * TS + i + ky) * TS + j0) * 128) + p * 256 + c16 * 16;
    int db = ((ky * 34 + p) * 256 + c16 * 16) ^ ((p & 7) << 4);
    *(uint4*)((char*)at + db) = *(const uint4*)src;
  }
  __syncthreads();
  f32x4 acc[2][2] = {};
#pragma unroll
  for (int tap = 0; tap < 9; ++tap) {
    int ky = tap / 3, kx = tap - 3 * ky;
    int pxa = lr + kx, pxb = 16 + lr + kx;
#pragma unroll
    for (int cq = 0; cq < 4; ++cq) {
      bfrag a0 = *(const bfrag*)((const char*)at +
          (((ky * 34 + pxa) * 256 + cq * 64 + lq * 16) ^ ((pxa & 7) << 4)));
      bfrag a1 = *(const bfrag*)((const char*)at +
          (((ky * 34 + pxb) * 256 + cq * 64 + lq * 16) ^ ((pxb & 7) << 4)));
      int s = tap * 4 + cq;
      bfrag b0 = loadB(wp + (size_t)(s * 4 + wv * 2) * 512 + lane * 8);
      bfrag b1 = loadB(wp + (size_t)(s * 4 + wv * 2 + 1) * 512 + lane * 8);
      MFMA4(a0, a1, b0, b1, acc);
    }
  }
  float* dst = offb + ((size_t)b * HW_ + (size_t)i * W_ + j0) * 64;
#pragma unroll
  for (int nf = 0; nf < 2; ++nf) {
    int o = ob + nf * 16 + lr;
    float bias = (o < 54) ? boff[o] : 0.f;
#pragma unroll
    for (int mf = 0; mf < 2; ++mf)
#pragma unroll
      for (int jj = 0; jj < 4; ++jj) {
        int pix = mf * 16 + 4 * lq + jj;
        float v = (o < 54) ? acc[mf][nf][jj] + bias : 0.f;
        dst[(size_t)pix * 64 + o] = v;
      }
  }
}

// ---------------------------------------------------------------------------
// K4: DCNv2 — 16 pixels/block, 512 threads; phase-2 split 2 o-halves x
// 4 k-quarters: each wave 4 o-tiles x 9 ksteps (4x fewer A-reads, 4-way
// MFMA ILP), k-partials reduced through LDS.
// ---------------------------------------------------------------------------
__global__ __launch_bounds__(512)
void k_dcn(const ushort_t* __restrict__ t3p, const float* __restrict__ offb,
           const ushort_t* __restrict__ wp, const float* __restrict__ bdcn,
           const float* __restrict__ bnp, ushort_t* __restrict__ t4cl) {
  __shared__ ushort_t val[16 * VSTR];    // 37120 B (reused as 24KB f32 staging)
  __shared__ int   pre_b[288];
  __shared__ uint2 pre_w[288];
  int tid = threadIdx.x;
  int j0 = blockIdx.x * 16, i = blockIdx.y, b = blockIdx.z;

  // phase 0: per-(pix,g,k) precompute (288 tasks)
  if (tid < 288) {
    int t = tid;
    int pix = t / 18, gk = t - pix * 18;
    int g = gk / 9, k = gk - 9 * g;
    int ky = k / 3, kx = k - 3 * ky;
    int j = j0 + pix;
    const float* ob_ = offb + ((size_t)b * HW_ + (size_t)i * W_ + j) * 64;
    float dy = ob_[gk];
    float dx = ob_[18 + gk];
    float ml = ob_[36 + gk];
    float mk = 1.f / (1.f + __expf(-ml));
    float py = (float)(i - 1 + ky) + dy;
    float px = (float)(j - 1 + kx) + dx;
    float fy = floorf(py), fx = floorf(px);
    float wy = py - fy, wx = px - fx;
    int y0 = (int)fy, x0 = (int)fx;
    bool yv0 = (unsigned)y0 < 96u, yv1 = (unsigned)(y0 + 1) < 96u;
    bool xv0 = (unsigned)x0 < 96u, xv1 = (unsigned)(x0 + 1) < 96u;
    float w00 = (yv0 && xv0) ? (1.f - wy) * (1.f - wx) * mk : 0.f;
    float w01 = (yv0 && xv1) ? (1.f - wy) * wx * mk : 0.f;
    float w10 = (yv1 && xv0) ? wy * (1.f - wx) * mk : 0.f;
    float w11 = (yv1 && xv1) ? wy * wx * mk : 0.f;
    int yb = min(max(y0, -1), 95), xb = min(max(x0, -1), 95);
    pre_b[t] = (((yb + 1) * TS + xb + 1) * 128 + g * 64) * 2;
    pre_w[t] = make_uint2((unsigned)f2bf(w00) | ((unsigned)f2bf(w01) << 16),
                          (unsigned)f2bf(w10) | ((unsigned)f2bf(w11) << 16));
  }
  __syncthreads();

  // phase 1: group gq (16 lanes) -> (pix = gq>>1, g = gq&1); walk k=0..8
  {
    int gq = tid >> 4;                 // 0..31
    int c16 = tid & 15;
    int pix = gq >> 1, g = gq & 1;
    const char* imgb = (const char*)(t3p + (size_t)b * TS * TS * 128) + c16 * 8;
    int bidx = pix * 18 + g * 9;
    char* vrow = (char*)val + pix * (VSTR * 2) + g * 128 + c16 * 8;
#pragma unroll
    for (int k = 0; k < 9; ++k) {
      int gb = pre_b[bidx + k];
      uint2 ww = pre_w[bidx + k];
      const char* pA = imgb + gb;
      uint2 d00 = *(const uint2*)(pA);
      uint2 d01 = *(const uint2*)(pA + 256);
      uint2 d10 = *(const uint2*)(pA + TS * 256);
      uint2 d11 = *(const uint2*)(pA + TS * 256 + 256);
      float w00 = loF(ww.x), w01 = hiF(ww.x);
      float w10 = loF(ww.y), w11 = hiF(ww.y);
      unsigned o2[2];
#pragma unroll
      for (int t = 0; t < 2; ++t) {
        unsigned e00 = ((const unsigned*)&d00)[t];
        unsigned e01 = ((const unsigned*)&d01)[t];
        unsigned e10 = ((const unsigned*)&d10)[t];
        unsigned e11 = ((const unsigned*)&d11)[t];
        float slo = loF(e00) * w00 + loF(e01) * w01 + loF(e10) * w10 + loF(e11) * w11;
        float shi = hiF(e00) * w00 + hiF(e01) * w01 + hiF(e10) * w10 + hiF(e11) * w11;
        unsigned u0 = __builtin_bit_cast(unsigned, slo) + 0x8000u;
        unsigned u1 = __builtin_bit_cast(unsigned, shi) + 0x8000u;
        o2[t] = __builtin_amdgcn_perm(u1, u0, 0x07060302u);
      }
      *(uint2*)(vrow + k * 256) = make_uint2(o2[0], o2[1]);
    }
  }
  __syncthreads();

  // phase 2: wave (wo, wk): 4 o-tiles (obq = wo*4+ot) over 9 ksteps
  int lane = tid & 63, wv = tid >> 6;
  int lr = lane & 15, lq = lane >> 4;
  int wo = wv & 1, wk = wv >> 1;
  f32x4 acc[4] = {};
#pragma unroll
  for (int s9 = 0; s9 < 9; ++s9) {
    int s = wk * 9 + s9;
    bfrag a0 = *(const bfrag*)&val[lr * VSTR + 32 * s + 8 * lq];
#pragma unroll
    for (int ot = 0; ot < 4; ++ot) {
      bfrag b0 = loadB(wp + (size_t)(s * 8 + wo * 4 + ot) * 512 + lane * 8);
      acc[ot] = __builtin_amdgcn_mfma_f32_16x16x32_bf16(a0, b0, acc[ot], 0, 0, 0);
    }
  }
  __syncthreads();                       // all val reads complete
  float* red = (float*)val;              // 6 slots x 1024 f32 = 24KB
  if (wk > 0) {
    float* dst = red + (size_t)((wk - 1) * 2 + wo) * 1024 + lane * 4;
#pragma unroll
    for (int ot = 0; ot < 4; ++ot)
      *(f32x4*)(dst + ot * 256) = acc[ot];
  }
  __syncthreads();
  if (wk == 0) {
#pragma unroll
    for (int w = 0; w < 3; ++w) {
      const float* src = red + (size_t)(w * 2 + wo) * 1024 + lane * 4;
#pragma unroll
      for (int ot = 0; ot < 4; ++ot) {
        f32x4 v = *(const f32x4*)(src + ot * 256);
        acc[ot] += v;
      }
    }
    ushort_t* dst = t4cl + ((size_t)(b * 96 + i) * 96 + j0) * 128;
#pragma unroll
    for (int ot = 0; ot < 4; ++ot) {
      int o = wo * 64 + ot * 16 + lr;
      float inv = bnp[o] * rsqrtf(bnp[384 + o] + EPS);
      float bb = bnp[128 + o] - bnp[256 + o] * inv;
      float bd = bdcn[o];
#pragma unroll
      for (int jj = 0; jj < 4; ++jj) {
        int pix = 4 * lq + jj;
        float r = (acc[ot][jj] + bd) * inv + bb;
        r = r >= 0.f ? r : NEG * r;
        dst[(size_t)pix * 128 + o] = f2bf(r);
      }
    }
  }
}

// ---------------------------------------------------------------------------
// K5: 1x1 (128->128)+BN+LReLU + 1x1 s2 residual (64->128)+BN -> out (NCHW fp32)
// ---------------------------------------------------------------------------
__global__ __launch_bounds__(256)
void k_final(const ushort_t* __restrict__ t4cl, const ushort_t* __restrict__ xclp,
             const ushort_t* __restrict__ wpc2, const ushort_t* __restrict__ wpds,
             const float* __restrict__ bn2p, const float* __restrict__ bndsp,
             float* __restrict__ outp) {
  __shared__ float ol[128 * 36];
  int tid = threadIdx.x, lane = tid & 63, wv = tid >> 6;
  int lr = lane & 15, lq = lane >> 4, ob = wv * 32;
  int j0 = blockIdx.x * 32, i = blockIdx.y, b = blockIdx.z;
  f32x4 acc[2][2] = {};
  f32x4 acs[2][2] = {};
  {
    const ushort_t* rowp = t4cl + ((size_t)(b * 96 + i) * 96 + j0) * 128;
#pragma unroll
    for (int s = 0; s < 4; ++s) {
      bfrag a0 = loadB(rowp + (size_t)lr * 128 + s * 32 + 8 * lq);
      bfrag a1 = loadB(rowp + (size_t)(16 + lr) * 128 + s * 32 + 8 * lq);
      bfrag b0 = loadB(wpc2 + (size_t)(s * 8 + wv * 2) * 512 + lane * 8);
      bfrag b1 = loadB(wpc2 + (size_t)(s * 8 + wv * 2 + 1) * 512 + lane * 8);
      MFMA4(a0, a1, b0, b1, acc);
    }
  }
  {
    const ushort_t* rowx = xclp + (size_t)(b * XS + 2 * i + 1) * XS * 64;
    const ushort_t* pa = rowx + (size_t)(2 * (j0 + lr) + 1) * 64 + 8 * lq;
    const ushort_t* pb = rowx + (size_t)(2 * (j0 + 16 + lr) + 1) * 64 + 8 * lq;
#pragma unroll
    for (int s = 0; s < 2; ++s) {
      bfrag a0 = loadB(pa + s * 32);
      bfrag a1 = loadB(pb + s * 32);
      bfrag b0 = loadB(wpds + (size_t)(s * 8 + wv * 2) * 512 + lane * 8);
      bfrag b1 = loadB(wpds + (size_t)(s * 8 + wv * 2 + 1) * 512 + lane * 8);
      MFMA4(a0, a1, b0, b1, acs);
    }
  }
#pragma unroll
  for (int nf = 0; nf < 2; ++nf) {
    int o = ob + nf * 16 + lr;
    float i2 = bn2p[o] * rsqrtf(bn2p[384 + o] + EPS);
    float b2 = bn2p[128 + o] - bn2p[256 + o] * i2;
    float id = bndsp[o] * rsqrtf(bndsp[384 + o] + EPS);
    float bd = bndsp[128 + o] - bndsp[256 + o] * id;
#pragma unroll
    for (int mf = 0; mf < 2; ++mf)
#pragma unroll
      for (int jj = 0; jj < 4; ++jj) {
        int pix = mf * 16 + 4 * lq + jj;
        float h = acc[mf][nf][jj] * i2 + b2;
        h = h >= 0.f ? h : NEG * h;
        float res = acs[mf][nf][jj] * id + bd;
        ol[o * 36 + pix] = res + h;
      }
  }
  __syncthreads();
#pragma unroll
  for (int r = 0; r < 4; ++r) {
    int idx = r * 256 + tid;
    int o = idx >> 3, p4 = idx & 7;
    f32x4 v = *(const f32x4*)&ol[o * 36 + p4 * 4];
    *(f32x4*)&outp[((size_t)(b * C_ + o) * H_ + i) * W_ + j0 + p4 * 4] = v;
  }
}

// ---------------------------------------------------------------------------
extern "C" void kernel_launch(void* const* d_in, const int* in_sizes, int n_in,
                              void* d_out, int out_size, void* d_ws, size_t ws_size,
                              hipStream_t stream) {
  const float* x     = (const float*)d_in[0];
  const float* w_r1  = (const float*)d_in[1];
  const float* bn_r1 = (const float*)d_in[2];
  const float* w_r2  = (const float*)d_in[3];
  const float* bn_r2 = (const float*)d_in[4];
  const float* w_rs  = (const float*)d_in[5];
  const float* bn_rs = (const float*)d_in[6];
  const float* w_off = (const float*)d_in[7];
  const float* b_off = (const float*)d_in[8];
  const float* w_dcn = (const float*)d_in[9];
  const float* b_dcn = (const float*)d_in[10];
  const float* bn1   = (const float*)d_in[11];
  const float* w_c2  = (const float*)d_in[12];
  const float* bn2   = (const float*)d_in[13];
  const float* w_ds  = (const float*)d_in[14];
  const float* bn_ds = (const float*)d_in[15];
  float* out = (float*)d_out;

  // workspace layout (ushort elems); total ~38.0 MiB
  ushort_t* base  = (ushort_t*)d_ws;
  ushort_t* xclp  = base;                        // 9634816
  ushort_t* t1p   = base + 9634816;              // 4917248
  ushort_t* t3p   = base + 14552064;             // 4917248
  ushort_t* wp_r1 = base + 19469312;             // 73728
  ushort_t* wp_r2 = wp_r1 + 73728;               // 147456
  ushort_t* wp_off= wp_r2 + 147456;              // 73728
  ushort_t* wp_dcn= wp_off + 73728;              // 147456
  ushort_t* wp_rs = wp_dcn + 147456;             // 8192
  ushort_t* wp_c2 = wp_rs + 8192;                // 16384
  ushort_t* wp_ds = wp_c2 + 16384;               // 8192
  float*    offb  = (float*)t1p;                 // aliased (t1p dead after conv2)
  ushort_t* t4cl  = t1p;                         // aliases offb (per-pixel RAW safe)

  k_prep<<<1883, 256, 0, stream>>>(w_r1, w_r2, w_off, w_dcn, w_rs, w_c2, w_ds,
                                   wp_r1, wp_r2, wp_off, wp_dcn, wp_rs, wp_c2,
                                   wp_ds, xclp, t1p, t3p);

  k_xcl    <<<dim3(3, 192, 4), dim3(64, 4), 0, stream>>>(x, xclp);
  k_conv1  <<<dim3(3, 96, 4), 256, 0, stream>>>(xclp, wp_r1, bn_r1, t1p);
  k_conv2  <<<dim3(3, 96, 4), 256, 0, stream>>>(t1p, xclp, wp_r2, wp_rs, bn_r2, bn_rs, t3p);
  k_convoff<<<dim3(3, 96, 4), 128, 0, stream>>>(t3p, wp_off, b_off, offb);
  k_dcn    <<<dim3(6, 96, 4), 512, 0, stream>>>(t3p, offb, wp_dcn, b_dcn, bn1, t4cl);
  k_final  <<<dim3(3, 96, 4), 256, 0, stream>>>(t4cl, xclp, wp_c2, wp_ds, bn2, bn_ds, out);
}

// Round 13
// 127.709 us; speedup vs baseline: 1.0132x; 1.0132x over previous
//
#include <hip/hip_runtime.h>
#include <hip/hip_bf16.h>
#include <cstdint>

#define EPS 1e-5f
#define NEG 0.1f

using bfrag = __attribute__((ext_vector_type(8))) short;   // 8 bf16
using f32x4 = __attribute__((ext_vector_type(4))) float;
typedef unsigned short ushort_t;

// geometry
constexpr int B_  = 4,  CIN = 64, H0 = 192, W0 = 192;
constexpr int C_  = 128, H_ = 96, W_ = 96;
constexpr int HW_ = H_ * W_;      // 9216
constexpr int HW0 = H0 * W0;      // 36864
constexpr int XS  = 194;          // padded xcl dim (1-px halo)
constexpr int TS  = 98;           // padded t1/t3 dim (1-px halo)
constexpr int VSTR = 1160;        // dcn val row stride (bf16)

__device__ __forceinline__ ushort_t f2bf(float f) {
  unsigned u = __builtin_bit_cast(unsigned, f);
  u += 0x7fffu + ((u >> 16) & 1u);
  return (ushort_t)(u >> 16);
}
__device__ __forceinline__ float loF(unsigned d) {
  return __builtin_bit_cast(float, d << 16);
}
__device__ __forceinline__ float hiF(unsigned d) {
  return __builtin_bit_cast(float, d & 0xFFFF0000u);
}
__device__ __forceinline__ bfrag loadB(const ushort_t* p) {
  return *(const bfrag*)p;
}

#define MFMA4(A0, A1, B0, B1, ACC)                                             \
  ACC[0][0] = __builtin_amdgcn_mfma_f32_16x16x32_bf16(A0, B0, ACC[0][0], 0, 0, 0); \
  ACC[0][1] = __builtin_amdgcn_mfma_f32_16x16x32_bf16(A0, B1, ACC[0][1], 0, 0, 0); \
  ACC[1][0] = __builtin_amdgcn_mfma_f32_16x16x32_bf16(A1, B0, ACC[1][0], 0, 0, 0); \
  ACC[1][1] = __builtin_amdgcn_mfma_f32_16x16x32_bf16(A1, B1, ACC[1][1], 0, 0, 0);

// ---------------------------------------------------------------------------
// k_prep: wave-order weight packing + halo zeroing, ONE launch (1883 blocks).
// ---------------------------------------------------------------------------
__global__ __launch_bounds__(256)
void k_prep(const float* __restrict__ w_r1, const float* __restrict__ w_r2,
            const float* __restrict__ w_off, const float* __restrict__ w_dcn,
            const float* __restrict__ w_rs, const float* __restrict__ w_c2,
            const float* __restrict__ w_ds,
            ushort_t* __restrict__ wp_r1, ushort_t* __restrict__ wp_r2,
            ushort_t* __restrict__ wp_off, ushort_t* __restrict__ wp_dcn,
            ushort_t* __restrict__ wp_rs, ushort_t* __restrict__ wp_c2,
            ushort_t* __restrict__ wp_ds,
            ushort_t* __restrict__ xclp, ushort_t* __restrict__ t1p,
            ushort_t* __restrict__ t3p) {
  int bi = blockIdx.x;
  int tid = (int)threadIdx.x;
  auto pack3w = [&](const float* w, ushort_t* wp, int O, int C, int Opad, int b0) {
    int idx = (bi - b0) * 256 + tid;
    int e = idx & 7;
    int lane = (idx >> 3) & 63;
    int fb = idx >> 9;
    int OBQ = Opad / 16;
    int obq = fb % OBQ, s = fb / OBQ;
    int lr = lane & 15, lq = lane >> 4;
    int o = obq * 16 + lr;
    int cq = s % (C / 32), tap = s / (C / 32);
    int c = cq * 32 + lq * 8 + e;
    wp[idx] = (o < O) ? f2bf(w[((size_t)o * C + c) * 9 + tap]) : (ushort_t)0;
  };
  auto pack1w = [&](const float* w, ushort_t* wp, int O, int C, int Opad, int b0) {
    int idx = (bi - b0) * 256 + tid;
    int e = idx & 7;
    int lane = (idx >> 3) & 63;
    int fb = idx >> 9;
    int OBQ = Opad / 16;
    int obq = fb % OBQ, s = fb / OBQ;
    int lr = lane & 15, lq = lane >> 4;
    int o = obq * 16 + lr;
    int c = s * 32 + lq * 8 + e;
    wp[idx] = (o < O) ? f2bf(w[(size_t)o * C + c]) : (ushort_t)0;
  };
  auto border = [&](ushort_t* buf, int N, int C, int b0) {
    int idx = (bi - b0) * 256 + tid;
    int per = 4 * N - 4;
    if (idx >= per * 4) return;
    int b = idx / per, e = idx - b * per;
    int r, s;
    if (e < N) { r = 0; s = e; }
    else if (e < 2 * N) { r = N - 1; s = e - N; }
    else if (e < 3 * N - 2) { r = e - 2 * N + 1; s = 0; }
    else { r = e - (3 * N - 2) + 1; s = N - 1; }
    uint4* p = (uint4*)(buf + ((size_t)(b * N + r) * N + s) * C);
#pragma unroll
    for (int t = 0; t < 16; ++t) { if (t < C / 8) p[t] = make_uint4(0, 0, 0, 0); }
  };
  if      (bi <  288) pack3w(w_r1,  wp_r1, 128,  64, 128, 0);
  else if (bi <  864) pack3w(w_r2,  wp_r2, 128, 128, 128, 288);
  else if (bi < 1152) pack3w(w_off, wp_off, 54, 128,  64, 864);
  else if (bi < 1728) pack3w(w_dcn, wp_dcn, 128, 128, 128, 1152);
  else if (bi < 1760) pack1w(w_rs,  wp_rs, 128,  64, 128, 1728);
  else if (bi < 1824) pack1w(w_c2,  wp_c2, 128, 128, 128, 1760);
  else if (bi < 1856) pack1w(w_ds,  wp_ds, 128,  64, 128, 1824);
  else if (bi < 1869) border(xclp, XS, 64, 1856);
  else if (bi < 1876) border(t1p, TS, 128, 1869);
  else                border(t3p, TS, 128, 1876);
}

// ---------------------------------------------------------------------------
// x [4,64,192,192] fp32 NCHW -> xclp [4,194,194,64] bf16 (interior)
// ---------------------------------------------------------------------------
__global__ __launch_bounds__(256)
void k_xcl(const float* __restrict__ x, ushort_t* __restrict__ xclp) {
  __shared__ float tile[64][65];
  int tx = threadIdx.x, ty = threadIdx.y;
  int cx = blockIdx.x, y = blockIdx.y, b = blockIdx.z;
  const float* src = x + (size_t)b * CIN * HW0 + (size_t)y * W0 + cx * 64;
#pragma unroll
  for (int r = 0; r < 16; ++r) {
    int ch = r * 4 + ty;
    tile[ch][tx] = src[(size_t)ch * HW0 + tx];
  }
  __syncthreads();
  ushort_t* dst = xclp + ((size_t)(b * XS + y + 1) * XS + cx * 64 + 1) * 64;
#pragma unroll
  for (int r = 0; r < 16; ++r) {
    int pp = r * 4 + ty;
    dst[(size_t)pp * 64 + tx] = f2bf(tile[tx][pp]);
  }
}

// ---------------------------------------------------------------------------
// K1: conv3x3 s2 p1 (64->128) + BN + LReLU.  xclp -> t1p.
// LDS-staged A (swizzle key (px>>1)&7), wave-order B.
// ---------------------------------------------------------------------------
__global__ __launch_bounds__(256)
void k_conv1(const ushort_t* __restrict__ xclp, const ushort_t* __restrict__ wp,
             const float* __restrict__ bnp, ushort_t* __restrict__ t1p) {
  __shared__ ushort_t at[3 * 66 * 64];     // 25344 B
  int tid = threadIdx.x, lane = tid & 63, wv = tid >> 6;
  int lr = lane & 15, lq = lane >> 4, ob = wv * 32;
  int j0 = blockIdx.x * 32, i = blockIdx.y, b = blockIdx.z;
  for (int t = tid; t < 1584; t += 256) {
    int ky = t / 528, r = t - ky * 528;
    int p = r >> 3, c8 = r & 7;
    const char* src = (const char*)(xclp +
        ((size_t)(b * XS + 2 * i + ky) * XS + 2 * j0) * 64) + p * 128 + c8 * 16;
    int db = ((ky * 66 + p) * 128 + c8 * 16) ^ (((p >> 1) & 7) << 4);
    *(uint4*)((char*)at + db) = *(const uint4*)src;
  }
  __syncthreads();
  f32x4 acc[2][2] = {};
#pragma unroll
  for (int tap = 0; tap < 9; ++tap) {
    int ky = tap / 3, kx = tap - 3 * ky;
    int pxa = 2 * lr + kx, pxb = 2 * (16 + lr) + kx;
#pragma unroll
    for (int cq = 0; cq < 2; ++cq) {
      bfrag a0 = *(const bfrag*)((const char*)at +
          (((ky * 66 + pxa) * 128 + cq * 64 + lq * 16) ^ (((pxa >> 1) & 7) << 4)));
      bfrag a1 = *(const bfrag*)((const char*)at +
          (((ky * 66 + pxb) * 128 + cq * 64 + lq * 16) ^ (((pxb >> 1) & 7) << 4)));
      int s = tap * 2 + cq;
      bfrag b0 = loadB(wp + (size_t)(s * 8 + wv * 2) * 512 + lane * 8);
      bfrag b1 = loadB(wp + (size_t)(s * 8 + wv * 2 + 1) * 512 + lane * 8);
      MFMA4(a0, a1, b0, b1, acc);
    }
  }
  ushort_t* dst = t1p + ((size_t)(b * TS + i + 1) * TS + j0 + 1) * 128;
#pragma unroll
  for (int nf = 0; nf < 2; ++nf) {
    int o = ob + nf * 16 + lr;
    float inv = bnp[o] * rsqrtf(bnp[384 + o] + EPS);
    float bb = bnp[128 + o] - bnp[256 + o] * inv;
#pragma unroll
    for (int mf = 0; mf < 2; ++mf)
#pragma unroll
      for (int jj = 0; jj < 4; ++jj) {
        int pix = mf * 16 + 4 * lq + jj;
        float r = acc[mf][nf][jj] * inv + bb;
        r = r >= 0.f ? r : NEG * r;
        dst[(size_t)pix * 128 + o] = f2bf(r);
      }
  }
}

// ---------------------------------------------------------------------------
// K2: conv3x3 s1 p1 (128->128)+BN + 1x1 s2 shortcut+BN, add, LReLU -> t3p
// ---------------------------------------------------------------------------
__global__ __launch_bounds__(256)
void k_conv2(const ushort_t* __restrict__ t1p, const ushort_t* __restrict__ xclp,
             const ushort_t* __restrict__ wp2, const ushort_t* __restrict__ wprs,
             const float* __restrict__ bn2p, const float* __restrict__ bnsp,
             ushort_t* __restrict__ t3p) {
  __shared__ ushort_t at[3 * 34 * 128];    // 26112 B
  int tid = threadIdx.x, lane = tid & 63, wv = tid >> 6;
  int lr = lane & 15, lq = lane >> 4, ob = wv * 32;
  int j0 = blockIdx.x * 32, i = blockIdx.y, b = blockIdx.z;
  for (int t = tid; t < 1632; t += 256) {
    int ky = t / 544, r = t - ky * 544;
    int p = r >> 4, c16 = r & 15;
    const char* src = (const char*)(t1p +
        ((size_t)(b * TS + i + ky) * TS + j0) * 128) + p * 256 + c16 * 16;
    int db = ((ky * 34 + p) * 256 + c16 * 16) ^ ((p & 7) << 4);
    *(uint4*)((char*)at + db) = *(const uint4*)src;
  }
  __syncthreads();
  f32x4 acc[2][2] = {};
  f32x4 acs[2][2] = {};
#pragma unroll
  for (int tap = 0; tap < 9; ++tap) {
    int ky = tap / 3, kx = tap - 3 * ky;
    int pxa = lr + kx, pxb = 16 + lr + kx;
#pragma unroll
    for (int cq = 0; cq < 4; ++cq) {
      bfrag a0 = *(const bfrag*)((const char*)at +
          (((ky * 34 + pxa) * 256 + cq * 64 + lq * 16) ^ ((pxa & 7) << 4)));
      bfrag a1 = *(const bfrag*)((const char*)at +
          (((ky * 34 + pxb) * 256 + cq * 64 + lq * 16) ^ ((pxb & 7) << 4)));
      int s = tap * 4 + cq;
      bfrag b0 = loadB(wp2 + (size_t)(s * 8 + wv * 2) * 512 + lane * 8);
      bfrag b1 = loadB(wp2 + (size_t)(s * 8 + wv * 2 + 1) * 512 + lane * 8);
      MFMA4(a0, a1, b0, b1, acc);
    }
  }
  {
    const ushort_t* rowp = xclp + (size_t)(b * XS + 2 * i + 1) * XS * 64;
    const ushort_t* pa = rowp + (size_t)(2 * (j0 + lr) + 1) * 64 + 8 * lq;
    const ushort_t* pb = rowp + (size_t)(2 * (j0 + 16 + lr) + 1) * 64 + 8 * lq;
#pragma unroll
    for (int sq = 0; sq < 2; ++sq) {
      bfrag a0 = loadB(pa + sq * 32);
      bfrag a1 = loadB(pb + sq * 32);
      bfrag b0 = loadB(wprs + (size_t)(sq * 8 + wv * 2) * 512 + lane * 8);
      bfrag b1 = loadB(wprs + (size_t)(sq * 8 + wv * 2 + 1) * 512 + lane * 8);
      MFMA4(a0, a1, b0, b1, acs);
    }
  }
  ushort_t* dst = t3p + ((size_t)(b * TS + i + 1) * TS + j0 + 1) * 128;
#pragma unroll
  for (int nf = 0; nf < 2; ++nf) {
    int o = ob + nf * 16 + lr;
    float i2 = bn2p[o] * rsqrtf(bn2p[384 + o] + EPS);
    float b2 = bn2p[128 + o] - bn2p[256 + o] * i2;
    float is = bnsp[o] * rsqrtf(bnsp[384 + o] + EPS);
    float bs = bnsp[128 + o] - bnsp[256 + o] * is;
#pragma unroll
    for (int mf = 0; mf < 2; ++mf)
#pragma unroll
      for (int jj = 0; jj < 4; ++jj) {
        int pix = mf * 16 + 4 * lq + jj;
        float h = acc[mf][nf][jj] * i2 + b2 + acs[mf][nf][jj] * is + bs;
        h = h >= 0.f ? h : NEG * h;
        dst[(size_t)pix * 128 + o] = f2bf(h);
      }
  }
}

// ---------------------------------------------------------------------------
// K3: conv3x3 s1 p1 (128->54, pad 64) + bias -> offb; LDS-staged like conv2.
// ---------------------------------------------------------------------------
__global__ __launch_bounds__(128)
void k_convoff(const ushort_t* __restrict__ t3p, const ushort_t* __restrict__ wp,
               const float* __restrict__ boff, float* __restrict__ offb) {
  __shared__ ushort_t at[3 * 34 * 128];    // 26112 B
  int tid = threadIdx.x, lane = tid & 63, wv = tid >> 6;
  int lr = lane & 15, lq = lane >> 4, ob = wv * 32;
  int j0 = blockIdx.x * 32, i = blockIdx.y, b = blockIdx.z;
  for (int t = tid; t < 1632; t += 128) {
    int ky = t / 544, r = t - ky * 544;
    int p = r >> 4, c16 = r & 15;
    const char* src = (const char*)(t3p +
        ((size_t)(b * TS + i + ky) * TS + j0) * 128) + p * 256 + c16 * 16;
    int db = ((ky * 34 + p) * 256 + c16 * 16) ^ ((p & 7) << 4);
    *(uint4*)((char*)at + db) = *(const uint4*)src;
  }
  __syncthreads();
  f32x4 acc[2][2] = {};
#pragma unroll
  for (int tap = 0; tap < 9; ++tap) {
    int ky = tap / 3, kx = tap - 3 * ky;
    int pxa = lr + kx, pxb = 16 + lr + kx;
#pragma unroll
    for (int cq = 0; cq < 4; ++cq) {
      bfrag a0 = *(const bfrag*)((const char*)at +
          (((ky * 34 + pxa) * 256 + cq * 64 + lq * 16) ^ ((pxa & 7) << 4)));
      bfrag a1 = *(const bfrag*)((const char*)at +
          (((ky * 34 + pxb) * 256 + cq * 64 + lq * 16) ^ ((pxb & 7) << 4)));
      int s = tap * 4 + cq;
      bfrag b0 = loadB(wp + (size_t)(s * 4 + wv * 2) * 512 + lane * 8);
      bfrag b1 = loadB(wp + (size_t)(s * 4 + wv * 2 + 1) * 512 + lane * 8);
      MFMA4(a0, a1, b0, b1, acc);
    }
  }
  float* dst = offb + ((size_t)b * HW_ + (size_t)i * W_ + j0) * 64;
#pragma unroll
  for (int nf = 0; nf < 2; ++nf) {
    int o = ob + nf * 16 + lr;
    float bias = (o < 54) ? boff[o] : 0.f;
#pragma unroll
    for (int mf = 0; mf < 2; ++mf)
#pragma unroll
      for (int jj = 0; jj < 4; ++jj) {
        int pix = mf * 16 + 4 * lq + jj;
        float v = (o < 54) ? acc[mf][nf][jj] + bias : 0.f;
        dst[(size_t)pix * 64 + o] = v;
      }
  }
}

// ---------------------------------------------------------------------------
// K4: DCNv2 — 16 pixels/block, 512 threads. Barrier-light gather:
// each 16-lane group's lanes 0..8 compute its own 9 offset entries in
// registers (no phase-0 barrier); phase 1 fetches them via __shfl and runs
// a 2-deep load pipeline fenced by sched_barrier(0). One __syncthreads.
// ---------------------------------------------------------------------------
__global__ __launch_bounds__(512)
void k_dcn(const ushort_t* __restrict__ t3p, const float* __restrict__ offb,
           const ushort_t* __restrict__ wp, const float* __restrict__ bdcn,
           const float* __restrict__ bnp, ushort_t* __restrict__ t4cl) {
  __shared__ ushort_t val[16 * VSTR];    // 37120 B (only LDS)
  int tid = threadIdx.x;
  int j0 = blockIdx.x * 16, i = blockIdx.y, b = blockIdx.z;
  int lane = tid & 63, wv = tid >> 6;
  int gq = tid >> 4;          // group 0..31: (pix = gq>>1, g = gq&1)
  int c16 = tid & 15;
  int pix = gq >> 1, g = gq & 1;
  int gl = (gq & 3) * 16;     // group base lane within wave

  // per-lane offset precompute: lane c16<9 owns tap k=c16 of (pix,g)
  int my_b = 0; unsigned my_w0 = 0, my_w1 = 0;
  if (c16 < 9) {
    int k = c16, gk = g * 9 + k;
    int ky = k / 3, kx = k - 3 * ky;
    int j = j0 + pix;
    const float* ob_ = offb + ((size_t)b * HW_ + (size_t)i * W_ + j) * 64;
    float dy = ob_[gk];
    float dx = ob_[18 + gk];
    float ml = ob_[36 + gk];
    float mk = 1.f / (1.f + __expf(-ml));
    float py = (float)(i - 1 + ky) + dy;
    float px = (float)(j - 1 + kx) + dx;
    float fy = floorf(py), fx = floorf(px);
    float wy = py - fy, wx = px - fx;
    int y0 = (int)fy, x0 = (int)fx;
    bool yv0 = (unsigned)y0 < 96u, yv1 = (unsigned)(y0 + 1) < 96u;
    bool xv0 = (unsigned)x0 < 96u, xv1 = (unsigned)(x0 + 1) < 96u;
    float w00 = (yv0 && xv0) ? (1.f - wy) * (1.f - wx) * mk : 0.f;
    float w01 = (yv0 && xv1) ? (1.f - wy) * wx * mk : 0.f;
    float w10 = (yv1 && xv0) ? wy * (1.f - wx) * mk : 0.f;
    float w11 = (yv1 && xv1) ? wy * wx * mk : 0.f;
    int yb = min(max(y0, -1), 95), xb = min(max(x0, -1), 95);
    my_b = (((yb + 1) * TS + xb + 1) * 128 + g * 64) * 2;
    my_w0 = (unsigned)f2bf(w00) | ((unsigned)f2bf(w01) << 16);
    my_w1 = (unsigned)f2bf(w10) | ((unsigned)f2bf(w11) << 16);
  }

  const char* imgb = (const char*)(t3p + (size_t)b * TS * TS * 128) + c16 * 8;
  char* vrow = (char*)val + pix * (VSTR * 2) + g * 128 + c16 * 8;

  // phase 1: 2-deep pipelined gather, metadata via wave shuffles
  int gb_c = __shfl(my_b, gl + 0, 64);
  unsigned w0_c = (unsigned)__shfl((int)my_w0, gl + 0, 64);
  unsigned w1_c = (unsigned)__shfl((int)my_w1, gl + 0, 64);
  const char* pC = imgb + gb_c;
  uint2 d00 = *(const uint2*)pC;
  uint2 d01 = *(const uint2*)(pC + 256);
  uint2 d10 = *(const uint2*)(pC + TS * 256);
  uint2 d11 = *(const uint2*)(pC + TS * 256 + 256);
#pragma unroll
  for (int k = 0; k < 9; ++k) {
    uint2 n00 = {}, n01 = {}, n10 = {}, n11 = {};
    unsigned w0_n = 0, w1_n = 0;
    if (k < 8) {
      int gb_n = __shfl(my_b, gl + k + 1, 64);
      w0_n = (unsigned)__shfl((int)my_w0, gl + k + 1, 64);
      w1_n = (unsigned)__shfl((int)my_w1, gl + k + 1, 64);
      const char* pN = imgb + gb_n;
      n00 = *(const uint2*)pN;
      n01 = *(const uint2*)(pN + 256);
      n10 = *(const uint2*)(pN + TS * 256);
      n11 = *(const uint2*)(pN + TS * 256 + 256);
    }
    __builtin_amdgcn_sched_barrier(0);   // pin next-iter loads before blend
    float w00 = loF(w0_c), w01 = hiF(w0_c);
    float w10 = loF(w1_c), w11 = hiF(w1_c);
    unsigned o2[2];
#pragma unroll
    for (int t = 0; t < 2; ++t) {
      unsigned e00 = ((const unsigned*)&d00)[t];
      unsigned e01 = ((const unsigned*)&d01)[t];
      unsigned e10 = ((const unsigned*)&d10)[t];
      unsigned e11 = ((const unsigned*)&d11)[t];
      float slo = loF(e00) * w00 + loF(e01) * w01 + loF(e10) * w10 + loF(e11) * w11;
      float shi = hiF(e00) * w00 + hiF(e01) * w01 + hiF(e10) * w10 + hiF(e11) * w11;
      unsigned u0 = __builtin_bit_cast(unsigned, slo) + 0x8000u;
      unsigned u1 = __builtin_bit_cast(unsigned, shi) + 0x8000u;
      o2[t] = __builtin_amdgcn_perm(u1, u0, 0x07060302u);
    }
    *(uint2*)(vrow + k * 256) = make_uint2(o2[0], o2[1]);
    d00 = n00; d01 = n01; d10 = n10; d11 = n11;
    w0_c = w0_n; w1_c = w1_n;
  }
  __syncthreads();

  // phase 2: MFMA out[16 pix][128 o]; 8 waves x 16 o-cols; wave-order B
  int lr = lane & 15, lq = lane >> 4, ob = wv * 16;
  f32x4 acc = {};
  for (int s = 0; s < 36; ++s) {
    bfrag a0 = *(const bfrag*)&val[lr * VSTR + 32 * s + 8 * lq];
    bfrag b0 = loadB(wp + (size_t)(s * 8 + wv) * 512 + lane * 8);
    acc = __builtin_amdgcn_mfma_f32_16x16x32_bf16(a0, b0, acc, 0, 0, 0);
  }

  // epilogue: bias + BN + LReLU, NHWC bf16 store
  {
    ushort_t* dst = t4cl + ((size_t)(b * 96 + i) * 96 + j0) * 128;
    int o = ob + lr;
    float inv = bnp[o] * rsqrtf(bnp[384 + o] + EPS);
    float bb = bnp[128 + o] - bnp[256 + o] * inv;
    float bd = bdcn[o];
#pragma unroll
    for (int jj = 0; jj < 4; ++jj) {
      int pixw = 4 * lq + jj;
      float r = (acc[jj] + bd) * inv + bb;
      r = r >= 0.f ? r : NEG * r;
      dst[(size_t)pixw * 128 + o] = f2bf(r);
    }
  }
}

// ---------------------------------------------------------------------------
// K5: 1x1 (128->128)+BN+LReLU + 1x1 s2 residual (64->128)+BN -> out (NCHW fp32)
// ---------------------------------------------------------------------------
__global__ __launch_bounds__(256)
void k_final(const ushort_t* __restrict__ t4cl, const ushort_t* __restrict__ xclp,
             const ushort_t* __restrict__ wpc2, const ushort_t* __restrict__ wpds,
             const float* __restrict__ bn2p, const float* __restrict__ bndsp,
             float* __restrict__ outp) {
  __shared__ float ol[128 * 36];
  int tid = threadIdx.x, lane = tid & 63, wv = tid >> 6;
  int lr = lane & 15, lq = lane >> 4, ob = wv * 32;
  int j0 = blockIdx.x * 32, i = blockIdx.y, b = blockIdx.z;
  f32x4 acc[2][2] = {};
  f32x4 acs[2][2] = {};
  {
    const ushort_t* rowp = t4cl + ((size_t)(b * 96 + i) * 96 + j0) * 128;
#pragma unroll
    for (int s = 0; s < 4; ++s) {
      bfrag a0 = loadB(rowp + (size_t)lr * 128 + s * 32 + 8 * lq);
      bfrag a1 = loadB(rowp + (size_t)(16 + lr) * 128 + s * 32 + 8 * lq);
      bfrag b0 = loadB(wpc2 + (size_t)(s * 8 + wv * 2) * 512 + lane * 8);
      bfrag b1 = loadB(wpc2 + (size_t)(s * 8 + wv * 2 + 1) * 512 + lane * 8);
      MFMA4(a0, a1, b0, b1, acc);
    }
  }
  {
    const ushort_t* rowx = xclp + (size_t)(b * XS + 2 * i + 1) * XS * 64;
    const ushort_t* pa = rowx + (size_t)(2 * (j0 + lr) + 1) * 64 + 8 * lq;
    const ushort_t* pb = rowx + (size_t)(2 * (j0 + 16 + lr) + 1) * 64 + 8 * lq;
#pragma unroll
    for (int s = 0; s < 2; ++s) {
      bfrag a0 = loadB(pa + s * 32);
      bfrag a1 = loadB(pb + s * 32);
      bfrag b0 = loadB(wpds + (size_t)(s * 8 + wv * 2) * 512 + lane * 8);
      bfrag b1 = loadB(wpds + (size_t)(s * 8 + wv * 2 + 1) * 512 + lane * 8);
      MFMA4(a0, a1, b0, b1, acs);
    }
  }
#pragma unroll
  for (int nf = 0; nf < 2; ++nf) {
    int o = ob + nf * 16 + lr;
    float i2 = bn2p[o] * rsqrtf(bn2p[384 + o] + EPS);
    float b2 = bn2p[128 + o] - bn2p[256 + o] * i2;
    float id = bndsp[o] * rsqrtf(bndsp[384 + o] + EPS);
    float bd = bndsp[128 + o] - bndsp[256 + o] * id;
#pragma unroll
    for (int mf = 0; mf < 2; ++mf)
#pragma unroll
      for (int jj = 0; jj < 4; ++jj) {
        int pix = mf * 16 + 4 * lq + jj;
        float h = acc[mf][nf][jj] * i2 + b2;
        h = h >= 0.f ? h : NEG * h;
        float res = acs[mf][nf][jj] * id + bd;
        ol[o * 36 + pix] = res + h;
      }
  }
  __syncthreads();
#pragma unroll
  for (int r = 0; r < 4; ++r) {
    int idx = r * 256 + tid;
    int o = idx >> 3, p4 = idx & 7;
    f32x4 v = *(const f32x4*)&ol[o * 36 + p4 * 4];
    *(f32x4*)&outp[((size_t)(b * C_ + o) * H_ + i) * W_ + j0 + p4 * 4] = v;
  }
}

// ---------------------------------------------------------------------------
extern "C" void kernel_launch(void* const* d_in, const int* in_sizes, int n_in,
                              void* d_out, int out_size, void* d_ws, size_t ws_size,
                              hipStream_t stream) {
  const float* x     = (const float*)d_in[0];
  const float* w_r1  = (const float*)d_in[1];
  const float* bn_r1 = (const float*)d_in[2];
  const float* w_r2  = (const float*)d_in[3];
  const float* bn_r2 = (const float*)d_in[4];
  const float* w_rs  = (const float*)d_in[5];
  const float* bn_rs = (const float*)d_in[6];
  const float* w_off = (const float*)d_in[7];
  const float* b_off = (const float*)d_in[8];
  const float* w_dcn = (const float*)d_in[9];
  const float* b_dcn = (const float*)d_in[10];
  const float* bn1   = (const float*)d_in[11];
  const float* w_c2  = (const float*)d_in[12];
  const float* bn2   = (const float*)d_in[13];
  const float* w_ds  = (const float*)d_in[14];
  const float* bn_ds = (const float*)d_in[15];
  float* out = (float*)d_out;

  // workspace layout (ushort elems); total ~38.0 MiB
  ushort_t* base  = (ushort_t*)d_ws;
  ushort_t* xclp  = base;                        // 9634816
  ushort_t* t1p   = base + 9634816;              // 4917248
  ushort_t* t3p   = base + 14552064;             // 4917248
  ushort_t* wp_r1 = base + 19469312;             // 73728
  ushort_t* wp_r2 = wp_r1 + 73728;               // 147456
  ushort_t* wp_off= wp_r2 + 147456;              // 73728
  ushort_t* wp_dcn= wp_off + 73728;              // 147456
  ushort_t* wp_rs = wp_dcn + 147456;             // 8192
  ushort_t* wp_c2 = wp_rs + 8192;                // 16384
  ushort_t* wp_ds = wp_c2 + 16384;               // 8192
  float*    offb  = (float*)t1p;                 // aliased (t1p dead after conv2)
  ushort_t* t4cl  = t1p;                         // aliases offb (per-pixel RAW safe)

  k_prep<<<1883, 256, 0, stream>>>(w_r1, w_r2, w_off, w_dcn, w_rs, w_c2, w_ds,
                                   wp_r1, wp_r2, wp_off, wp_dcn, wp_rs, wp_c2,
                                   wp_ds, xclp, t1p, t3p);

  k_xcl    <<<dim3(3, 192, 4), dim3(64, 4), 0, stream>>>(x, xclp);
  k_conv1  <<<dim3(3, 96, 4), 256, 0, stream>>>(xclp, wp_r1, bn_r1, t1p);
  k_conv2  <<<dim3(3, 96, 4), 256, 0, stream>>>(t1p, xclp, wp_r2, wp_rs, bn_r2, bn_rs, t3p);
  k_convoff<<<dim3(3, 96, 4), 128, 0, stream>>>(t3p, wp_off, b_off, offb);
  k_dcn    <<<dim3(6, 96, 4), 512, 0, stream>>>(t3p, offb, wp_dcn, b_dcn, bn1, t4cl);
  k_final  <<<dim3(3, 96, 4), 256, 0, stream>>>(t4cl, xclp, wp_c2, wp_ds, bn2, bn_ds, out);
}